// Round 7
// baseline (253.466 us; speedup 1.0000x reference)
//
#include <hip/hip_runtime.h>
#include <stdint.h>

typedef __attribute__((ext_vector_type(8))) short s16x8;
typedef __attribute__((ext_vector_type(4))) float f32x4;

#define MFMA16(a, b, c) __builtin_amdgcn_mfma_f32_16x16x32_bf16((a), (b), (c), 0, 0, 0)

// ---------- helpers ----------
__device__ __forceinline__ unsigned short f2bf(float f) {
    unsigned int u = __float_as_uint(f);
    return (unsigned short)((u + 0x7FFFu + ((u >> 16) & 1u)) >> 16);
}
__device__ __forceinline__ float bf2f(unsigned short h) {
    return __uint_as_float(((unsigned int)h) << 16);
}
__device__ __forceinline__ void cvt8(unsigned short* dst, const float* src) {
    const float4 f0 = *(const float4*)(src);
    const float4 f1 = *(const float4*)(src + 4);
    s16x8 v;
    v[0] = (short)f2bf(f0.x); v[1] = (short)f2bf(f0.y);
    v[2] = (short)f2bf(f0.z); v[3] = (short)f2bf(f0.w);
    v[4] = (short)f2bf(f1.x); v[5] = (short)f2bf(f1.y);
    v[6] = (short)f2bf(f1.z); v[7] = (short)f2bf(f1.w);
    *(s16x8*)dst = v;
}

// ---------- bulk fp32 -> bf16 ----------
__global__ __launch_bounds__(256) void cvt_bf16(const float* __restrict__ in,
                                                unsigned short* __restrict__ out) {
    const int i = (blockIdx.x * 256 + threadIdx.x) * 8;
    cvt8(&out[i], &in[i]);
}

// ---------- GEMM 128x128: C[m][n] = sum_k A[m][k] * B[n][k], bf16 in ----------
// 256 thr / 4 waves (2x2); wave = 64x64 = 4x4 mfma_16x16x32 tiles; BK=64.
// __launch_bounds__(256, 1): min 1 wave/EU -> VGPR cap 512, NO accumulator
// spill (round-6 default heuristic capped at 76 VGPR and spilled acc to
// scratch: WRITE_SIZE 3x, MfmaUtil 4.5%).
template <bool OUT_F32>
__global__ __launch_bounds__(256, 1) void gemm128(const unsigned short* __restrict__ A,
                                                  const unsigned short* __restrict__ Bw,
                                                  void* __restrict__ Cout, int K, int N) {
    const int bm = blockIdx.x, bn = blockIdx.y;
    const int t = threadIdx.x;
    const int lane = t & 63, w = t >> 6;
    const int quad = lane >> 4, col = lane & 15;
    const int wm = (w >> 1) * 64, wn = (w & 1) * 64;

    __shared__ alignas(16) unsigned short As[128][72];  // +8 pad: 2-way alias only
    __shared__ alignas(16) unsigned short Bs[128][72];

    f32x4 acc[4][4];
#pragma unroll
    for (int i = 0; i < 4; ++i)
#pragma unroll
        for (int j = 0; j < 4; ++j) acc[i][j] = (f32x4){0.f, 0.f, 0.f, 0.f};

    const int r0 = t >> 3;        // 0..31
    const int c0 = (t & 7) * 8;   // 0..56
    const unsigned short* Ap = A + (size_t)(bm * 128 + r0) * K + c0;
    const unsigned short* Bp = Bw + (size_t)(bn * 128 + r0) * K + c0;

    uint4 areg[4], breg[4];
#pragma unroll
    for (int rr = 0; rr < 4; ++rr) {
        areg[rr] = *(const uint4*)(Ap + (size_t)(rr * 32) * K);
        breg[rr] = *(const uint4*)(Bp + (size_t)(rr * 32) * K);
    }

    for (int k0 = 0; k0 < K; k0 += 64) {
        __syncthreads();   // previous iter's LDS reads done
#pragma unroll
        for (int rr = 0; rr < 4; ++rr) {
            *(uint4*)&As[r0 + rr * 32][c0] = areg[rr];
            *(uint4*)&Bs[r0 + rr * 32][c0] = breg[rr];
        }
        if (k0 + 64 < K) {
#pragma unroll
            for (int rr = 0; rr < 4; ++rr) {   // issue next loads before compute
                areg[rr] = *(const uint4*)(Ap + (size_t)(rr * 32) * K + k0 + 64);
                breg[rr] = *(const uint4*)(Bp + (size_t)(rr * 32) * K + k0 + 64);
            }
        }
        __syncthreads();
#pragma unroll
        for (int s = 0; s < 2; ++s) {
            s16x8 af[4], bfr[4];
#pragma unroll
            for (int i = 0; i < 4; ++i) {
                af[i]  = *(const s16x8*)&As[wm + i * 16 + col][s * 32 + quad * 8];
                bfr[i] = *(const s16x8*)&Bs[wn + i * 16 + col][s * 32 + quad * 8];
            }
#pragma unroll
            for (int i = 0; i < 4; ++i)
#pragma unroll
                for (int j = 0; j < 4; ++j)
                    acc[i][j] = MFMA16(af[i], bfr[j], acc[i][j]);
        }
    }
    const int rowb = bm * 128 + wm + quad * 4;
    const int colb = bn * 128 + wn + col;
#pragma unroll
    for (int i = 0; i < 4; ++i)
#pragma unroll
        for (int j = 0; j < 4; ++j)
#pragma unroll
            for (int r = 0; r < 4; ++r) {
                size_t off = (size_t)(rowb + i * 16 + r) * N + colb + j * 16;
                if (OUT_F32) ((float*)Cout)[off] = acc[i][j][r];
                else ((unsigned short*)Cout)[off] = f2bf(acc[i][j][r]);
            }
}

// ---------- LayerNorm over 1152, IN-PLACE (bf16), + extract vT — vectorized ----------
__global__ __launch_bounds__(256) void ln_split(unsigned short* __restrict__ qkvn,
                                                const float* __restrict__ gamma,
                                                const float* __restrict__ beta,
                                                unsigned short* __restrict__ vT) {
    const int row = blockIdx.x;  // b*2048 + l
    const int b = row >> 11, l = row & 2047;
    unsigned short* rp = qkvn + (size_t)row * 1152;
    const int t = threadIdx.x;
    const bool act = t < 144;    // 144 * 8 = 1152

    float fv[8];
    float s = 0.f, s2 = 0.f;
    if (act) {
        s16x8 v = *(const s16x8*)&rp[t * 8];
#pragma unroll
        for (int e = 0; e < 8; ++e) {
            fv[e] = bf2f((unsigned short)v[e]);
            s += fv[e];
            s2 += fv[e] * fv[e];
        }
    } else {
#pragma unroll
        for (int e = 0; e < 8; ++e) fv[e] = 0.f;
    }
#pragma unroll
    for (int off = 32; off; off >>= 1) {
        s += __shfl_down(s, off);
        s2 += __shfl_down(s2, off);
    }
    __shared__ float red[8];
    const int lane = t & 63, w = t >> 6;
    if (lane == 0) { red[w] = s; red[w + 4] = s2; }
    __syncthreads();
    s = red[0] + red[1] + red[2] + red[3];
    s2 = red[4] + red[5] + red[6] + red[7];
    const float mu = s * (1.0f / 1152.0f);
    float var = s2 * (1.0f / 1152.0f) - mu * mu;
    var = fmaxf(var, 0.0f);
    const float rstd = rsqrtf(var + 1e-5f);

    if (act) {
        float4 g0 = *(const float4*)&gamma[t * 8];
        float4 g1 = *(const float4*)&gamma[t * 8 + 4];
        float4 e0 = *(const float4*)&beta[t * 8];
        float4 e1 = *(const float4*)&beta[t * 8 + 4];
        const float gg[8] = {g0.x, g0.y, g0.z, g0.w, g1.x, g1.y, g1.z, g1.w};
        const float bb[8] = {e0.x, e0.y, e0.z, e0.w, e1.x, e1.y, e1.z, e1.w};
        s16x8 o;
#pragma unroll
        for (int e = 0; e < 8; ++e)
            o[e] = (short)f2bf((fv[e] - mu) * rstd * gg[e] + bb[e]);
        *(s16x8*)&rp[t * 8] = o;
        if (t >= 8 && t < 16) {   // v head (cols 64..127) -> transposed copy
            const int d0 = t * 8 - 64;
#pragma unroll
            for (int e = 0; e < 8; ++e)
                vT[((size_t)(b * 64 + d0 + e)) * 2048 + l] = (unsigned short)o[e];
        }
    }
}

// ---------- Flash-style causal multi-query attention ----------
// Block: 512 thr / 8 waves, 2 heads x 64 q-rows; K/V staged once per tile for
// both heads (multi-query reuse). Double-buffered K/V + register prefetch:
// ONE __syncthreads per k-iter. Fixed-max softmax p = exp(s - 12)
// (shift-invariant; LN'd q,k with q pre-scaled 1/8 keep |s| <~ 9). Row-sum via
// MFMA vs ones. P round-trip is wave-private (in-order LDS, no barrier).
__global__ __launch_bounds__(512) void attn_kernel(const unsigned short* __restrict__ qkvn,
                                                   const unsigned short* __restrict__ vT,
                                                   unsigned short* __restrict__ obuf) {
    const int b = blockIdx.x >> 3, hp = blockIdx.x & 7;
    const int qb = 31 - blockIdx.y;  // longest tiles dispatched first
    const int t = threadIdx.x;
    const int lane = t & 63, w = t >> 6;
    const int quad = lane >> 4, col = lane & 15;
    const int hl = w >> 2, wq = w & 3;   // head-local, wave-in-head

    __shared__ alignas(16) unsigned short Ks[2][64][72];
    __shared__ alignas(16) unsigned short Vts[2][64][72];   // [d][j]
    __shared__ alignas(16) unsigned short PQ[8][16][72];    // Q-stage, then per-wave P

    unsigned short(*Qs)[72] = (unsigned short(*)[72])PQ;    // view as [128][72]

    const int rs = t >> 3;        // 0..63
    const int cs = (t & 7) * 8;   // 0..56

    // stage Q for both heads, pre-scaled by 1/8 (exact in bf16)
#pragma unroll
    for (int hh = 0; hh < 2; ++hh) {
        const unsigned short* qsrc =
            qkvn + (size_t)(b * 2048 + qb * 64 + rs) * 1152 + 128 + (hp * 2 + hh) * 64 + cs;
        s16x8 v = *(const s16x8*)qsrc;
#pragma unroll
        for (int e = 0; e < 8; ++e)
            v[e] = (short)f2bf(bf2f((unsigned short)v[e]) * 0.125f);
        *(s16x8*)&Qs[hh * 64 + rs][cs] = v;
    }
    __syncthreads();
    const s16x8 qf0 = *(const s16x8*)&Qs[hl * 64 + wq * 16 + col][quad * 8];
    const s16x8 qf1 = *(const s16x8*)&Qs[hl * 64 + wq * 16 + col][32 + quad * 8];

    // stage K/V tile 0
    const unsigned short* kbase = qkvn + (size_t)(b * 2048 + rs) * 1152 + cs;  // + kb*64*1152
    const unsigned short* vbase = vT + (size_t)(b * 64 + rs) * 2048 + cs;      // + kb*64
    *(uint4*)&Ks[0][rs][cs]  = *(const uint4*)(kbase);
    *(uint4*)&Vts[0][rs][cs] = *(const uint4*)(vbase);
    __syncthreads();  // KV0 visible; all Q-frag reads done -> PQ reusable as P

    s16x8 ones;
#pragma unroll
    for (int e = 0; e < 8; ++e) ones[e] = (short)0x3F80;  // bf16 1.0

    f32x4 Oacc[4];
    f32x4 lacc = {0.f, 0.f, 0.f, 0.f};
#pragma unroll
    for (int nt = 0; nt < 4; ++nt) Oacc[nt] = (f32x4){0.f, 0.f, 0.f, 0.f};

    const int qg = qb * 64 + wq * 16 + quad * 4;  // + r

    for (int kb = 0; kb <= qb; ++kb) {
        const int p = kb & 1;
        uint4 kreg, vreg;
        if (kb < qb) {  // issue next tile's global loads before compute
            kreg = *(const uint4*)(kbase + (size_t)(kb + 1) * 64 * 1152);
            vreg = *(const uint4*)(vbase + (kb + 1) * 64);
        }

        // S = (Q/8) K^T  (16 x 64 per wave)
        f32x4 S[4];
#pragma unroll
        for (int nt = 0; nt < 4; ++nt) {
            s16x8 kf0 = *(const s16x8*)&Ks[p][nt * 16 + col][quad * 8];
            s16x8 kf1 = *(const s16x8*)&Ks[p][nt * 16 + col][32 + quad * 8];
            f32x4 z = (f32x4){0.f, 0.f, 0.f, 0.f};
            z = MFMA16(qf0, kf0, z);
            z = MFMA16(qf1, kf1, z);
            S[nt] = z;
        }
        if (kb == qb) {  // causal mask on diagonal tile only
#pragma unroll
            for (int nt = 0; nt < 4; ++nt)
#pragma unroll
                for (int r = 0; r < 4; ++r)
                    if (kb * 64 + nt * 16 + col > qg + r) S[nt][r] = -1e30f;
        }

        // P = exp(S - 12): C-layout -> LDS -> A-layout (wave-private, no barrier)
#pragma unroll
        for (int nt = 0; nt < 4; ++nt)
#pragma unroll
            for (int r = 0; r < 4; ++r)
                PQ[w][quad * 4 + r][nt * 16 + col] = f2bf(__expf(S[nt][r] - 12.0f));

        const s16x8 pf0 = *(const s16x8*)&PQ[w][col][quad * 8];
        const s16x8 pf1 = *(const s16x8*)&PQ[w][col][32 + quad * 8];
        lacc = MFMA16(pf0, ones, lacc);
        lacc = MFMA16(pf1, ones, lacc);
#pragma unroll
        for (int nt = 0; nt < 4; ++nt) {
            s16x8 vf0 = *(const s16x8*)&Vts[p][nt * 16 + col][quad * 8];
            s16x8 vf1 = *(const s16x8*)&Vts[p][nt * 16 + col][32 + quad * 8];
            Oacc[nt] = MFMA16(pf0, vf0, Oacc[nt]);
            Oacc[nt] = MFMA16(pf1, vf1, Oacc[nt]);
        }

        if (kb < qb) {  // LDS-write prefetched tile into the other buffer
            *(uint4*)&Ks[p ^ 1][rs][cs]  = kreg;
            *(uint4*)&Vts[p ^ 1][rs][cs] = vreg;
        }
        __syncthreads();  // ONE barrier per iter
    }

    // epilogue: O / l  ->  obuf [b][l][h][64]  (bf16)
    const int h = hp * 2 + hl;
#pragma unroll
    for (int r = 0; r < 4; ++r) {
        float inv = 1.0f / lacc[r];
        size_t base = (((size_t)b * 2048 + qg + r) * 16 + h) * 64;
#pragma unroll
        for (int nt = 0; nt < 4; ++nt)
            obuf[base + nt * 16 + col] = f2bf(Oacc[nt][r] * inv);
    }
}

// ---------- launch ----------
extern "C" void kernel_launch(void* const* d_in, const int* in_sizes, int n_in,
                              void* d_out, int out_size, void* d_ws, size_t ws_size,
                              hipStream_t stream) {
    (void)in_sizes; (void)n_in; (void)out_size; (void)ws_size;
    const float* x     = (const float*)d_in[0];  // (2,2048,1024) fp32
    const float* Wqkv  = (const float*)d_in[1];  // (1152,1024)  fp32
    const float* gamma = (const float*)d_in[2];  // (1152,)      fp32
    const float* beta  = (const float*)d_in[3];  // (1152,)      fp32
    const float* Wfc   = (const float*)d_in[4];  // (1024,1024)  fp32
    float* out = (float*)d_out;                  // (2,2048,1024) fp32

    // ws >= 22,806,528 B (proven in round 5: fast path ran)
    char* ws = (char*)d_ws;
    unsigned short* xb   = (unsigned short*)ws;               // 8,388,608
    unsigned short* Wqb  = (unsigned short*)(ws + 8388608);   // 2,359,296
    unsigned short* Wfb  = (unsigned short*)(ws + 10747904);  // 2,097,152
    unsigned short* qkvn = (unsigned short*)(ws + 12845056);  // 9,437,184
    unsigned short* vT   = (unsigned short*)(ws + 22282240);  //   524,288
    unsigned short* abuf = (unsigned short*)ws;               // alias xb (dead after gemm1)

    cvt_bf16<<<dim3(2048), 256, 0, stream>>>(x, xb);
    cvt_bf16<<<dim3(576), 256, 0, stream>>>(Wqkv, Wqb);
    cvt_bf16<<<dim3(512), 256, 0, stream>>>(Wfc, Wfb);
    gemm128<false><<<dim3(32, 9), 256, 0, stream>>>(xb, Wqb, qkvn, 1024, 1152);
    ln_split<<<dim3(4096), 256, 0, stream>>>(qkvn, gamma, beta, vT);
    attn_kernel<<<dim3(16, 32), 512, 0, stream>>>(qkvn, vT, abuf);
    gemm128<true><<<dim3(32, 8), 256, 0, stream>>>(abuf, Wfb, out, 1024, 1024);
}

// Round 8
// 180.449 us; speedup vs baseline: 1.4046x; 1.4046x over previous
//
#include <hip/hip_runtime.h>
#include <stdint.h>

typedef __attribute__((ext_vector_type(8))) short s16x8;
typedef __attribute__((ext_vector_type(4))) float f32x4;

#define MFMA16(a, b, c) __builtin_amdgcn_mfma_f32_16x16x32_bf16((a), (b), (c), 0, 0, 0)

// ---------- helpers ----------
__device__ __forceinline__ unsigned short f2bf(float f) {
    unsigned int u = __float_as_uint(f);
    return (unsigned short)((u + 0x7FFFu + ((u >> 16) & 1u)) >> 16);
}
__device__ __forceinline__ float bf2f(unsigned short h) {
    return __uint_as_float(((unsigned int)h) << 16);
}
__device__ __forceinline__ void cvt8(unsigned short* dst, const float* src) {
    const float4 f0 = *(const float4*)(src);
    const float4 f1 = *(const float4*)(src + 4);
    s16x8 v;
    v[0] = (short)f2bf(f0.x); v[1] = (short)f2bf(f0.y);
    v[2] = (short)f2bf(f0.z); v[3] = (short)f2bf(f0.w);
    v[4] = (short)f2bf(f1.x); v[5] = (short)f2bf(f1.y);
    v[6] = (short)f2bf(f1.z); v[7] = (short)f2bf(f1.w);
    *(s16x8*)dst = v;
}
// async global->LDS DMA, 16 B per lane. lds must be WAVE-UNIFORM base;
// HW writes lane i at lds + i*16 (so LDS layout must be contiguous in lane
// order -- NO padding). Completion is forced by the vmcnt(0) drain that
// __syncthreads() emits.
__device__ __forceinline__ void gl_lds16(const unsigned short* g, unsigned short* l) {
    __builtin_amdgcn_global_load_lds(
        (const __attribute__((address_space(1))) unsigned int*)g,
        (__attribute__((address_space(3))) unsigned int*)l,
        16, 0, 0);
}

// ---------- bulk fp32 -> bf16 ----------
__global__ __launch_bounds__(256) void cvt_bf16(const float* __restrict__ in,
                                                unsigned short* __restrict__ out) {
    const int i = (blockIdx.x * 256 + threadIdx.x) * 8;
    cvt8(&out[i], &in[i]);
}

// ---------- GEMM 128x128 (m97-style async staging) ----------
// C[m][n] = sum_k A[m][k] * B[n][k], bf16 in. 256 thr / 4 waves (2x2); wave =
// 64x64 = 4x4 mfma_16x16x32; BK=64. Staging via global_load_lds width=16: no
// staging VGPRs at all (rounds 6-7 spilled the uint4 prefetch + acc to scratch:
// VGPR capped 76, WRITE_SIZE 3x, MfmaUtil 4.5%, 179us scratch cold-start).
// LDS tiles UNPADDED [128][64] as required by the DMA lane mapping.
template <bool OUT_F32>
__global__ __launch_bounds__(256) void gemm128a(const unsigned short* __restrict__ A,
                                                const unsigned short* __restrict__ Bw,
                                                void* __restrict__ Cout, int K, int N) {
    const int bm = blockIdx.x, bn = blockIdx.y;
    const int t = threadIdx.x;
    const int lane = t & 63, w = t >> 6;
    const int quad = lane >> 4, col = lane & 15;
    const int wm = (w >> 1) * 64, wn = (w & 1) * 64;

    __shared__ alignas(16) unsigned short As[128 * 64];  // 16 KB, unpadded
    __shared__ alignas(16) unsigned short Bs[128 * 64];  // 16 KB, unpadded

    f32x4 acc[4][4];
#pragma unroll
    for (int i = 0; i < 4; ++i)
#pragma unroll
        for (int j = 0; j < 4; ++j) acc[i][j] = (f32x4){0.f, 0.f, 0.f, 0.f};

    // DMA mapping: one call site = one wave instruction covering 8 rows
    // (64 lanes x 16 B = 8 rows x 64 shorts). Lane i -> row +(i>>3), col (i&7)*8.
    const int lrow = lane >> 3;       // 0..7
    const int lcol = (lane & 7) * 8;  // 0..56 shorts
    const unsigned short* Ap = A + (size_t)(bm * 128 + w * 8 + lrow) * K + lcol;
    const unsigned short* Bp = Bw + (size_t)(bn * 128 + w * 8 + lrow) * K + lcol;

    for (int k0 = 0; k0 < K; k0 += 64) {
        __syncthreads();  // previous iter's ds_reads done before overwrite
#pragma unroll
        for (int j = 0; j < 4; ++j) {  // 4 issues/wave each for A and B
            gl_lds16(Ap + (size_t)(j * 32) * K + k0, &As[(j * 32 + w * 8) * 64]);
            gl_lds16(Bp + (size_t)(j * 32) * K + k0, &Bs[(j * 32 + w * 8) * 64]);
        }
        __syncthreads();  // vmcnt(0) drain: DMA data visible
#pragma unroll
        for (int s = 0; s < 2; ++s) {
            s16x8 af[4], bfr[4];
#pragma unroll
            for (int i = 0; i < 4; ++i) {
                af[i]  = *(const s16x8*)&As[(wm + i * 16 + col) * 64 + s * 32 + quad * 8];
                bfr[i] = *(const s16x8*)&Bs[(wn + i * 16 + col) * 64 + s * 32 + quad * 8];
            }
#pragma unroll
            for (int i = 0; i < 4; ++i)
#pragma unroll
                for (int j = 0; j < 4; ++j)
                    acc[i][j] = MFMA16(af[i], bfr[j], acc[i][j]);
        }
    }
    const int rowb = bm * 128 + wm + quad * 4;
    const int colb = bn * 128 + wn + col;
#pragma unroll
    for (int i = 0; i < 4; ++i)
#pragma unroll
        for (int j = 0; j < 4; ++j)
#pragma unroll
            for (int r = 0; r < 4; ++r) {
                size_t off = (size_t)(rowb + i * 16 + r) * N + colb + j * 16;
                if (OUT_F32) ((float*)Cout)[off] = acc[i][j][r];
                else ((unsigned short*)Cout)[off] = f2bf(acc[i][j][r]);
            }
}

// ---------- LayerNorm over 1152, IN-PLACE (bf16), + extract vT — vectorized ----------
__global__ __launch_bounds__(256) void ln_split(unsigned short* __restrict__ qkvn,
                                                const float* __restrict__ gamma,
                                                const float* __restrict__ beta,
                                                unsigned short* __restrict__ vT) {
    const int row = blockIdx.x;  // b*2048 + l
    const int b = row >> 11, l = row & 2047;
    unsigned short* rp = qkvn + (size_t)row * 1152;
    const int t = threadIdx.x;
    const bool act = t < 144;    // 144 * 8 = 1152

    float fv[8];
    float s = 0.f, s2 = 0.f;
    if (act) {
        s16x8 v = *(const s16x8*)&rp[t * 8];
#pragma unroll
        for (int e = 0; e < 8; ++e) {
            fv[e] = bf2f((unsigned short)v[e]);
            s += fv[e];
            s2 += fv[e] * fv[e];
        }
    } else {
#pragma unroll
        for (int e = 0; e < 8; ++e) fv[e] = 0.f;
    }
#pragma unroll
    for (int off = 32; off; off >>= 1) {
        s += __shfl_down(s, off);
        s2 += __shfl_down(s2, off);
    }
    __shared__ float red[8];
    const int lane = t & 63, w = t >> 6;
    if (lane == 0) { red[w] = s; red[w + 4] = s2; }
    __syncthreads();
    s = red[0] + red[1] + red[2] + red[3];
    s2 = red[4] + red[5] + red[6] + red[7];
    const float mu = s * (1.0f / 1152.0f);
    float var = s2 * (1.0f / 1152.0f) - mu * mu;
    var = fmaxf(var, 0.0f);
    const float rstd = rsqrtf(var + 1e-5f);

    if (act) {
        float4 g0 = *(const float4*)&gamma[t * 8];
        float4 g1 = *(const float4*)&gamma[t * 8 + 4];
        float4 e0 = *(const float4*)&beta[t * 8];
        float4 e1 = *(const float4*)&beta[t * 8 + 4];
        const float gg[8] = {g0.x, g0.y, g0.z, g0.w, g1.x, g1.y, g1.z, g1.w};
        const float bb[8] = {e0.x, e0.y, e0.z, e0.w, e1.x, e1.y, e1.z, e1.w};
        s16x8 o;
#pragma unroll
        for (int e = 0; e < 8; ++e)
            o[e] = (short)f2bf((fv[e] - mu) * rstd * gg[e] + bb[e]);
        *(s16x8*)&rp[t * 8] = o;
        if (t >= 8 && t < 16) {   // v head (cols 64..127) -> transposed copy
            const int d0 = t * 8 - 64;
#pragma unroll
            for (int e = 0; e < 8; ++e)
                vT[((size_t)(b * 64 + d0 + e)) * 2048 + l] = (unsigned short)o[e];
        }
    }
}

// ---------- Flash-style causal multi-query attention ----------
// Block: 512 thr / 8 waves, 2 heads x 64 q-rows; K/V staged once per tile for
// both heads (multi-query reuse). Double-buffered K/V + register prefetch:
// ONE __syncthreads per k-iter. Fixed-max softmax p = exp(s - 12)
// (shift-invariant; LN'd q,k with q pre-scaled 1/8 keep |s| <~ 9). Row-sum via
// MFMA vs ones. P round-trip is wave-private (in-order LDS, no barrier).
__global__ __launch_bounds__(512) void attn_kernel(const unsigned short* __restrict__ qkvn,
                                                   const unsigned short* __restrict__ vT,
                                                   unsigned short* __restrict__ obuf) {
    const int b = blockIdx.x >> 3, hp = blockIdx.x & 7;
    const int qb = 31 - blockIdx.y;  // longest tiles dispatched first
    const int t = threadIdx.x;
    const int lane = t & 63, w = t >> 6;
    const int quad = lane >> 4, col = lane & 15;
    const int hl = w >> 2, wq = w & 3;   // head-local, wave-in-head

    __shared__ alignas(16) unsigned short Ks[2][64][72];
    __shared__ alignas(16) unsigned short Vts[2][64][72];   // [d][j]
    __shared__ alignas(16) unsigned short PQ[8][16][72];    // Q-stage, then per-wave P

    unsigned short(*Qs)[72] = (unsigned short(*)[72])PQ;    // view as [128][72]

    const int rs = t >> 3;        // 0..63
    const int cs = (t & 7) * 8;   // 0..56

    // stage Q for both heads, pre-scaled by 1/8 (exact in bf16)
#pragma unroll
    for (int hh = 0; hh < 2; ++hh) {
        const unsigned short* qsrc =
            qkvn + (size_t)(b * 2048 + qb * 64 + rs) * 1152 + 128 + (hp * 2 + hh) * 64 + cs;
        s16x8 v = *(const s16x8*)qsrc;
#pragma unroll
        for (int e = 0; e < 8; ++e)
            v[e] = (short)f2bf(bf2f((unsigned short)v[e]) * 0.125f);
        *(s16x8*)&Qs[hh * 64 + rs][cs] = v;
    }
    __syncthreads();
    const s16x8 qf0 = *(const s16x8*)&Qs[hl * 64 + wq * 16 + col][quad * 8];
    const s16x8 qf1 = *(const s16x8*)&Qs[hl * 64 + wq * 16 + col][32 + quad * 8];

    // stage K/V tile 0
    const unsigned short* kbase = qkvn + (size_t)(b * 2048 + rs) * 1152 + cs;  // + kb*64*1152
    const unsigned short* vbase = vT + (size_t)(b * 64 + rs) * 2048 + cs;      // + kb*64
    *(uint4*)&Ks[0][rs][cs]  = *(const uint4*)(kbase);
    *(uint4*)&Vts[0][rs][cs] = *(const uint4*)(vbase);
    __syncthreads();  // KV0 visible; all Q-frag reads done -> PQ reusable as P

    s16x8 ones;
#pragma unroll
    for (int e = 0; e < 8; ++e) ones[e] = (short)0x3F80;  // bf16 1.0

    f32x4 Oacc[4];
    f32x4 lacc = {0.f, 0.f, 0.f, 0.f};
#pragma unroll
    for (int nt = 0; nt < 4; ++nt) Oacc[nt] = (f32x4){0.f, 0.f, 0.f, 0.f};

    const int qg = qb * 64 + wq * 16 + quad * 4;  // + r

    for (int kb = 0; kb <= qb; ++kb) {
        const int p = kb & 1;
        uint4 kreg, vreg;
        if (kb < qb) {  // issue next tile's global loads before compute
            kreg = *(const uint4*)(kbase + (size_t)(kb + 1) * 64 * 1152);
            vreg = *(const uint4*)(vbase + (kb + 1) * 64);
        }

        // S = (Q/8) K^T  (16 x 64 per wave)
        f32x4 S[4];
#pragma unroll
        for (int nt = 0; nt < 4; ++nt) {
            s16x8 kf0 = *(const s16x8*)&Ks[p][nt * 16 + col][quad * 8];
            s16x8 kf1 = *(const s16x8*)&Ks[p][nt * 16 + col][32 + quad * 8];
            f32x4 z = (f32x4){0.f, 0.f, 0.f, 0.f};
            z = MFMA16(qf0, kf0, z);
            z = MFMA16(qf1, kf1, z);
            S[nt] = z;
        }
        if (kb == qb) {  // causal mask on diagonal tile only
#pragma unroll
            for (int nt = 0; nt < 4; ++nt)
#pragma unroll
                for (int r = 0; r < 4; ++r)
                    if (kb * 64 + nt * 16 + col > qg + r) S[nt][r] = -1e30f;
        }

        // P = exp(S - 12): C-layout -> LDS -> A-layout (wave-private, no barrier)
#pragma unroll
        for (int nt = 0; nt < 4; ++nt)
#pragma unroll
            for (int r = 0; r < 4; ++r)
                PQ[w][quad * 4 + r][nt * 16 + col] = f2bf(__expf(S[nt][r] - 12.0f));

        const s16x8 pf0 = *(const s16x8*)&PQ[w][col][quad * 8];
        const s16x8 pf1 = *(const s16x8*)&PQ[w][col][32 + quad * 8];
        lacc = MFMA16(pf0, ones, lacc);
        lacc = MFMA16(pf1, ones, lacc);
#pragma unroll
        for (int nt = 0; nt < 4; ++nt) {
            s16x8 vf0 = *(const s16x8*)&Vts[p][nt * 16 + col][quad * 8];
            s16x8 vf1 = *(const s16x8*)&Vts[p][nt * 16 + col][32 + quad * 8];
            Oacc[nt] = MFMA16(pf0, vf0, Oacc[nt]);
            Oacc[nt] = MFMA16(pf1, vf1, Oacc[nt]);
        }

        if (kb < qb) {  // LDS-write prefetched tile into the other buffer
            *(uint4*)&Ks[p ^ 1][rs][cs]  = kreg;
            *(uint4*)&Vts[p ^ 1][rs][cs] = vreg;
        }
        __syncthreads();  // ONE barrier per iter
    }

    // epilogue: O / l  ->  obuf [b][l][h][64]  (bf16)
    const int h = hp * 2 + hl;
#pragma unroll
    for (int r = 0; r < 4; ++r) {
        float inv = 1.0f / lacc[r];
        size_t base = (((size_t)b * 2048 + qg + r) * 16 + h) * 64;
#pragma unroll
        for (int nt = 0; nt < 4; ++nt)
            obuf[base + nt * 16 + col] = f2bf(Oacc[nt][r] * inv);
    }
}

// ---------- launch ----------
extern "C" void kernel_launch(void* const* d_in, const int* in_sizes, int n_in,
                              void* d_out, int out_size, void* d_ws, size_t ws_size,
                              hipStream_t stream) {
    (void)in_sizes; (void)n_in; (void)out_size; (void)ws_size;
    const float* x     = (const float*)d_in[0];  // (2,2048,1024) fp32
    const float* Wqkv  = (const float*)d_in[1];  // (1152,1024)  fp32
    const float* gamma = (const float*)d_in[2];  // (1152,)      fp32
    const float* beta  = (const float*)d_in[3];  // (1152,)      fp32
    const float* Wfc   = (const float*)d_in[4];  // (1024,1024)  fp32
    float* out = (float*)d_out;                  // (2,2048,1024) fp32

    // ws >= 22,806,528 B (proven in round 5: fast path ran)
    char* ws = (char*)d_ws;
    unsigned short* xb   = (unsigned short*)ws;               // 8,388,608
    unsigned short* Wqb  = (unsigned short*)(ws + 8388608);   // 2,359,296
    unsigned short* Wfb  = (unsigned short*)(ws + 10747904);  // 2,097,152
    unsigned short* qkvn = (unsigned short*)(ws + 12845056);  // 9,437,184
    unsigned short* vT   = (unsigned short*)(ws + 22282240);  //   524,288
    unsigned short* abuf = (unsigned short*)ws;               // alias xb (dead after gemm1)

    cvt_bf16<<<dim3(2048), 256, 0, stream>>>(x, xb);
    cvt_bf16<<<dim3(576), 256, 0, stream>>>(Wqkv, Wqb);
    cvt_bf16<<<dim3(512), 256, 0, stream>>>(Wfc, Wfb);
    gemm128a<false><<<dim3(32, 9), 256, 0, stream>>>(xb, Wqb, qkvn, 1024, 1152);
    ln_split<<<dim3(4096), 256, 0, stream>>>(qkvn, gamma, beta, vT);
    attn_kernel<<<dim3(16, 32), 512, 0, stream>>>(qkvn, vT, abuf);
    gemm128a<true><<<dim3(32, 8), 256, 0, stream>>>(abuf, Wfb, out, 1024, 1024);
}